// Round 1
// baseline (578.052 us; speedup 1.0000x reference)
//
#include <hip/hip_runtime.h>

#define B_  16
#define C_  384
#define CR_ 96
#define HW_ 12544          // 112*112
#define HW4_ 3136          // HW/4, divisible by 64

// ---------------------------------------------------------------------------
// Kernel 1: global average pool. One block per (b,c) plane.
// ---------------------------------------------------------------------------
__global__ __launch_bounds__(256) void se_pool(const float* __restrict__ x,
                                               float* __restrict__ s) {
    const int bc = blockIdx.x;
    const float4* __restrict__ p = (const float4*)(x + (size_t)bc * HW_);

    float sum = 0.f;
    for (int i = threadIdx.x; i < HW4_; i += 256) {
        float4 v = p[i];
        sum += (v.x + v.y) + (v.z + v.w);
    }
    // wave (64-lane) reduction
    #pragma unroll
    for (int off = 32; off > 0; off >>= 1)
        sum += __shfl_down(sum, off, 64);

    __shared__ float wsum[4];
    const int lane = threadIdx.x & 63;
    const int wid  = threadIdx.x >> 6;
    if (lane == 0) wsum[wid] = sum;
    __syncthreads();
    if (threadIdx.x == 0) {
        float t = (wsum[0] + wsum[1]) + (wsum[2] + wsum[3]);
        s[bc] = t * (1.0f / (float)HW_);
    }
}

// ---------------------------------------------------------------------------
// Kernel 2: fc1+ReLU, fc2+bias, hardsigmoid. One block per batch element.
// ---------------------------------------------------------------------------
__global__ __launch_bounds__(384) void se_fc(const float* __restrict__ s,
                                             const float* __restrict__ w1,
                                             const float* __restrict__ b1,
                                             const float* __restrict__ w2,
                                             const float* __restrict__ b2,
                                             float* __restrict__ scale) {
    const int b = blockIdx.x;
    const int t = threadIdx.x;

    __shared__ float sl[C_];
    __shared__ float hid[CR_];

    if (t < C_) sl[t] = s[b * C_ + t];
    __syncthreads();

    if (t < CR_) {
        float acc = b1[t];
        const float* __restrict__ wr = w1 + (size_t)t * C_;
        #pragma unroll 4
        for (int k = 0; k < C_; ++k) acc = fmaf(sl[k], wr[k], acc);
        hid[t] = fmaxf(acc, 0.f);
    }
    __syncthreads();

    {
        float acc = b2[t];
        const float* __restrict__ wr = w2 + (size_t)t * CR_;
        #pragma unroll 4
        for (int k = 0; k < CR_; ++k) acc = fmaf(hid[k], wr[k], acc);
        float g = acc * (1.0f / 6.0f) + 0.5f;          // hardsigmoid
        g = fminf(fmaxf(g, 0.f), 1.f);
        scale[b * C_ + t] = g;
    }
}

// ---------------------------------------------------------------------------
// Kernel 3: out[b,c,h,w] = x[b,c,h,w] * scale[b,c]. float4 per thread, exact
// grid. HW4_ % 64 == 0, so scale index is wave-uniform.
// ---------------------------------------------------------------------------
__global__ __launch_bounds__(256) void se_gate(const float* __restrict__ x,
                                               const float* __restrict__ scale,
                                               float* __restrict__ out) {
    const size_t i = (size_t)blockIdx.x * 256 + threadIdx.x;
    const int bc = (int)(i / HW4_);
    const float g = scale[bc];

    const float4* __restrict__ xp = (const float4*)x;
    float4* __restrict__ op = (float4*)out;

    float4 v = xp[i];
    v.x *= g; v.y *= g; v.z *= g; v.w *= g;
    op[i] = v;
}

// ---------------------------------------------------------------------------
extern "C" void kernel_launch(void* const* d_in, const int* in_sizes, int n_in,
                              void* d_out, int out_size, void* d_ws, size_t ws_size,
                              hipStream_t stream) {
    const float* x  = (const float*)d_in[0];
    const float* w1 = (const float*)d_in[1];
    const float* b1 = (const float*)d_in[2];
    const float* w2 = (const float*)d_in[3];
    const float* b2 = (const float*)d_in[4];
    float* out = (float*)d_out;

    float* s_buf     = (float*)d_ws;                 // B*C floats
    float* scale_buf = s_buf + B_ * C_;              // B*C floats

    // 1) pool: 6144 planes
    se_pool<<<B_ * C_, 256, 0, stream>>>(x, s_buf);

    // 2) fc chain: 16 blocks
    se_fc<<<B_, 384, 0, stream>>>(s_buf, w1, b1, w2, b2, scale_buf);

    // 3) gate: exact grid over all float4 elements
    const int n4      = B_ * C_ * HW4_;              // 19,267,584
    const int nblocks = n4 / 256;                    // 75,264 (exact)
    se_gate<<<nblocks, 256, 0, stream>>>(x, scale_buf, out);
}